// Round 2
// baseline (729.291 us; speedup 1.0000x reference)
//
#include <hip/hip_runtime.h>

#define NN 512
#define DD 256

__device__ __forceinline__ float waveReduceSum(float v) {
    #pragma unroll
    for (int off = 32; off > 0; off >>= 1)
        v += __shfl_xor(v, off, 64);
    return v;
}

// Kernel 1: rank-1 projections. One 64-lane wave computes one output element:
// lane i loads float4 at x[e*256 + i*4] (wave reads the full contiguous 1KB row),
// dots with its 4 preloaded weights, wave-reduces.
__global__ __launch_bounds__(256) void proj_kernel(
    const float* __restrict__ xq, const float* __restrict__ xk,
    const float* __restrict__ xv,
    const float* __restrict__ WQ, const float* __restrict__ WK,
    const float* __restrict__ WV,
    float* __restrict__ q, float* __restrict__ k, float* __restrict__ v)
{
    const int lane = threadIdx.x & 63;
    const int waveInBlock = threadIdx.x >> 6;
    const int globalWave = blockIdx.x * (blockDim.x >> 6) + waveInBlock;
    const int totalWaves = gridDim.x * (blockDim.x >> 6);

    const float4 wq = *(const float4*)(WQ + lane * 4);
    const float4 wk = *(const float4*)(WK + lane * 4);
    const float4 wv = *(const float4*)(WV + lane * 4);

    const int nElem = NN * NN;                 // 262144 = 2^18
    for (int task = globalWave; task < 3 * nElem; task += totalWaves) {
        const int t = task >> 18;              // tensor id
        const int e = task & (nElem - 1);      // element id
        const float* x; float4 w; float* o;
        if (t == 0)      { x = xq; w = wq; o = q; }
        else if (t == 1) { x = xk; w = wk; o = k; }
        else             { x = xv; w = wv; o = v; }
        const float4 xr = *(const float4*)(x + (size_t)e * DD + lane * 4);
        float p = xr.x * w.x + xr.y * w.y + xr.z * w.z + xr.w * w.w;
        p = waveReduceSum(p);
        if (lane == 0) o[e] = p;
    }
}

// Kernel 2: out[i,:] = softmax(q[i,:] @ k) @ v   (q,k,v are [512,512] fp32, L2-resident)
// One block of 256 threads per row i; each thread owns columns (tid, tid+256).
__global__ __launch_bounds__(256) void attn_kernel(
    const float* __restrict__ q, const float* __restrict__ k,
    const float* __restrict__ v, float* __restrict__ out)
{
    __shared__ float qrow[NN];
    __shared__ float p[NN];
    __shared__ float red[8];

    const int i = blockIdx.x;
    const int tid = threadIdx.x;
    const int lane = tid & 63;
    const int wid = tid >> 6;
    const int j0 = tid, j1 = tid + 256;

    qrow[j0] = q[i * NN + j0];
    qrow[j1] = q[i * NN + j1];
    __syncthreads();

    float acc0 = 0.f, acc1 = 0.f;
    #pragma unroll 8
    for (int l = 0; l < NN; ++l) {
        const float ql = qrow[l];               // LDS broadcast (conflict-free)
        acc0 = fmaf(ql, k[l * NN + j0], acc0);  // coalesced across lanes
        acc1 = fmaf(ql, k[l * NN + j1], acc1);
    }

    // row softmax over the 512 values (2 per thread)
    float m = fmaxf(acc0, acc1);
    #pragma unroll
    for (int off = 32; off > 0; off >>= 1)
        m = fmaxf(m, __shfl_xor(m, off, 64));
    if (lane == 0) red[wid] = m;
    __syncthreads();
    m = fmaxf(fmaxf(red[0], red[1]), fmaxf(red[2], red[3]));

    float e0 = __expf(acc0 - m);
    float e1 = __expf(acc1 - m);
    float s = e0 + e1;
    #pragma unroll
    for (int off = 32; off > 0; off >>= 1)
        s += __shfl_xor(s, off, 64);
    if (lane == 0) red[4 + wid] = s;            // disjoint slots from red[0..3]
    __syncthreads();
    s = red[4] + red[5] + red[6] + red[7];
    const float inv = 1.0f / s;
    p[j0] = e0 * inv;
    p[j1] = e1 * inv;
    __syncthreads();

    acc0 = 0.f; acc1 = 0.f;
    #pragma unroll 8
    for (int j = 0; j < NN; ++j) {
        const float pj = p[j];                  // LDS broadcast
        acc0 = fmaf(pj, v[j * NN + j0], acc0);  // coalesced across lanes
        acc1 = fmaf(pj, v[j * NN + j1], acc1);
    }
    out[i * NN + j0] = acc0;
    out[i * NN + j1] = acc1;
}

extern "C" void kernel_launch(void* const* d_in, const int* in_sizes, int n_in,
                              void* d_out, int out_size, void* d_ws, size_t ws_size,
                              hipStream_t stream) {
    const float* xq = (const float*)d_in[0];
    const float* xk = (const float*)d_in[1];
    const float* xv = (const float*)d_in[2];
    const float* WQ = (const float*)d_in[3];
    const float* WK = (const float*)d_in[4];
    const float* WV = (const float*)d_in[5];

    float* q = (float*)d_ws;                 // 1 MB
    float* k = q + NN * NN;                  // 1 MB
    float* v = k + NN * NN;                  // 1 MB
    float* o = (float*)d_out;

    proj_kernel<<<2048, 256, 0, stream>>>(xq, xk, xv, WQ, WK, WV, q, k, v);
    attn_kernel<<<NN, 256, 0, stream>>>(q, k, v, o);
}

// Round 4
// 718.977 us; speedup vs baseline: 1.0143x; 1.0143x over previous
//
#include <hip/hip_runtime.h>

#define NN 512
#define DD 256

// Kernel 1: rank-1 projections y[e] = x[e,:]·W for three tensors.
// A 16-lane group owns one element; lane (g,i) covers d = c*64 + i*4, c=0..3.
// Per wave-iteration: 4 consecutive elements, 4 independent float4 loads in
// flight (full 64B-line utilization), 4 FMA partials, 4-stage shfl reduce.
__global__ __launch_bounds__(256) void proj_kernel(
    const float* __restrict__ xq, const float* __restrict__ xk,
    const float* __restrict__ xv,
    const float* __restrict__ WQ, const float* __restrict__ WK,
    const float* __restrict__ WV,
    float* __restrict__ q, float* __restrict__ k, float* __restrict__ v)
{
    const int lane = threadIdx.x & 63;
    const int i = lane & 15;          // lane within 16-lane group
    const int g = lane >> 4;          // which of 4 elements this group owns
    const int gw = blockIdx.x * (blockDim.x >> 6) + (threadIdx.x >> 6);
    const int nw = gridDim.x * (blockDim.x >> 6);   // 8192 waves

    for (int t = 0; t < 3; ++t) {
        const float* __restrict__ x = (t == 0) ? xq : (t == 1) ? xk : xv;
        const float* __restrict__ W = (t == 0) ? WQ : (t == 1) ? WK : WV;
        float* __restrict__ o       = (t == 0) ? q  : (t == 1) ? k  : v;

        const float4 w0 = *(const float4*)(W +   0 + i * 4);
        const float4 w1 = *(const float4*)(W +  64 + i * 4);
        const float4 w2 = *(const float4*)(W + 128 + i * 4);
        const float4 w3 = *(const float4*)(W + 192 + i * 4);

        for (int s = gw; s < (NN * NN / 4); s += nw) {
            const int e0 = s * 4;
            const float4* px =
                (const float4*)(x + (size_t)(e0 + g) * DD + i * 4);
            // 4 independent 16B loads (imm offsets 0/256/512/768B)
            const float4 d0 = px[0];
            const float4 d1 = px[16];
            const float4 d2 = px[32];
            const float4 d3 = px[48];
            float p0 = d0.x*w0.x + d0.y*w0.y + d0.z*w0.z + d0.w*w0.w;
            float p1 = d1.x*w1.x + d1.y*w1.y + d1.z*w1.z + d1.w*w1.w;
            float p2 = d2.x*w2.x + d2.y*w2.y + d2.z*w2.z + d2.w*w2.w;
            float p3 = d3.x*w3.x + d3.y*w3.y + d3.z*w3.z + d3.w*w3.w;
            float p = (p0 + p1) + (p2 + p3);
            // reduce across the 16-lane group (4 stages, xor stays in-group)
            p += __shfl_xor(p, 1, 64);
            p += __shfl_xor(p, 2, 64);
            p += __shfl_xor(p, 4, 64);
            p += __shfl_xor(p, 8, 64);
            if (i == 0) o[e0 + g] = p;   // 4 lanes store 16 contiguous bytes
        }
    }
}

// Kernel 2: out[i,:] = softmax(q[i,:] @ k) @ v   (q,k,v are [512,512] fp32)
// One block of 256 threads per row i; each thread owns columns (tid, tid+256).
__global__ __launch_bounds__(256) void attn_kernel(
    const float* __restrict__ q, const float* __restrict__ k,
    const float* __restrict__ v, float* __restrict__ out)
{
    __shared__ float qrow[NN];
    __shared__ float p[NN];
    __shared__ float red[8];

    const int i = blockIdx.x;
    const int tid = threadIdx.x;
    const int lane = tid & 63;
    const int wid = tid >> 6;
    const int j0 = tid, j1 = tid + 256;

    qrow[j0] = q[i * NN + j0];
    qrow[j1] = q[i * NN + j1];
    __syncthreads();

    float acc0 = 0.f, acc1 = 0.f;
    #pragma unroll 8
    for (int l = 0; l < NN; ++l) {
        const float ql = qrow[l];               // LDS broadcast (conflict-free)
        acc0 = fmaf(ql, k[l * NN + j0], acc0);  // coalesced across lanes
        acc1 = fmaf(ql, k[l * NN + j1], acc1);
    }

    // row softmax over the 512 values (2 per thread)
    float m = fmaxf(acc0, acc1);
    #pragma unroll
    for (int off = 32; off > 0; off >>= 1)
        m = fmaxf(m, __shfl_xor(m, off, 64));
    if (lane == 0) red[wid] = m;
    __syncthreads();
    m = fmaxf(fmaxf(red[0], red[1]), fmaxf(red[2], red[3]));

    float e0 = __expf(acc0 - m);
    float e1 = __expf(acc1 - m);
    float s = e0 + e1;
    #pragma unroll
    for (int off = 32; off > 0; off >>= 1)
        s += __shfl_xor(s, off, 64);
    if (lane == 0) red[4 + wid] = s;            // disjoint slots from red[0..3]
    __syncthreads();
    s = red[4] + red[5] + red[6] + red[7];
    const float inv = 1.0f / s;
    p[j0] = e0 * inv;
    p[j1] = e1 * inv;
    __syncthreads();

    acc0 = 0.f; acc1 = 0.f;
    #pragma unroll 8
    for (int j = 0; j < NN; ++j) {
        const float pj = p[j];                  // LDS broadcast
        acc0 = fmaf(pj, v[j * NN + j0], acc0);  // coalesced across lanes
        acc1 = fmaf(pj, v[j * NN + j1], acc1);
    }
    out[i * NN + j0] = acc0;
    out[i * NN + j1] = acc1;
}

extern "C" void kernel_launch(void* const* d_in, const int* in_sizes, int n_in,
                              void* d_out, int out_size, void* d_ws, size_t ws_size,
                              hipStream_t stream) {
    const float* xq = (const float*)d_in[0];
    const float* xk = (const float*)d_in[1];
    const float* xv = (const float*)d_in[2];
    const float* WQ = (const float*)d_in[3];
    const float* WK = (const float*)d_in[4];
    const float* WV = (const float*)d_in[5];

    float* q = (float*)d_ws;                 // 1 MB
    float* k = q + NN * NN;                  // 1 MB
    float* v = k + NN * NN;                  // 1 MB
    float* o = (float*)d_out;

    proj_kernel<<<2048, 256, 0, stream>>>(xq, xk, xv, WQ, WK, WV, q, k, v);
    attn_kernel<<<NN, 256, 0, stream>>>(q, k, v, o);
}